// Round 1
// baseline (1153.796 us; speedup 1.0000x reference)
//
#include <hip/hip_runtime.h>
#include <hip/hip_bf16.h>
#include <math.h>

#define D 20
#define NROWS 4
#define TPB 256

// Per-row pipeline, fused:
//   h2 = relu(x @ M + c)   with M = W^T R (DxD), c = 1 + b @ R
//   h3 = h2 @ W^T + b
//   accumulate S += sum(h3), Q += sum(h3^2)
template <int NR>
__device__ __forceinline__ void process_rows(const float* __restrict__ xp,
                                             const float* sM, const float* sW,
                                             const float* sC, const float* sB,
                                             double& sd, double& qd) {
    float xr[NR][D];
    const float4* xp4 = (const float4*)xp;
#pragma unroll
    for (int rr = 0; rr < NR; ++rr) {
#pragma unroll
        for (int q = 0; q < D / 4; ++q) {
            float4 v = xp4[rr * (D / 4) + q];
            xr[rr][q * 4 + 0] = v.x;
            xr[rr][q * 4 + 1] = v.y;
            xr[rr][q * 4 + 2] = v.z;
            xr[rr][q * 4 + 3] = v.w;
        }
    }
    float h2[NR][D];
#pragma unroll
    for (int rr = 0; rr < NR; ++rr)
#pragma unroll
        for (int k = 0; k < D; ++k) h2[rr][k] = sC[k];

    const float4* M4 = (const float4*)sM;
#pragma unroll
    for (int d = 0; d < D; ++d) {
#pragma unroll
        for (int q = 0; q < D / 4; ++q) {
            float4 m = M4[d * (D / 4) + q];
#pragma unroll
            for (int rr = 0; rr < NR; ++rr) {
                h2[rr][q * 4 + 0] = fmaf(xr[rr][d], m.x, h2[rr][q * 4 + 0]);
                h2[rr][q * 4 + 1] = fmaf(xr[rr][d], m.y, h2[rr][q * 4 + 1]);
                h2[rr][q * 4 + 2] = fmaf(xr[rr][d], m.z, h2[rr][q * 4 + 2]);
                h2[rr][q * 4 + 3] = fmaf(xr[rr][d], m.w, h2[rr][q * 4 + 3]);
            }
        }
    }
#pragma unroll
    for (int rr = 0; rr < NR; ++rr)
#pragma unroll
        for (int k = 0; k < D; ++k) h2[rr][k] = fmaxf(h2[rr][k], 0.f);

    float srow[NR], qrow[NR];
#pragma unroll
    for (int rr = 0; rr < NR; ++rr) { srow[rr] = 0.f; qrow[rr] = 0.f; }

    const float4* W4 = (const float4*)sW;
#pragma unroll
    for (int j = 0; j < D; ++j) {
        float h3[NR];
#pragma unroll
        for (int rr = 0; rr < NR; ++rr) h3[rr] = sB[j];
#pragma unroll
        for (int q = 0; q < D / 4; ++q) {
            float4 w = W4[j * (D / 4) + q];
#pragma unroll
            for (int rr = 0; rr < NR; ++rr) {
                h3[rr] = fmaf(h2[rr][q * 4 + 0], w.x, h3[rr]);
                h3[rr] = fmaf(h2[rr][q * 4 + 1], w.y, h3[rr]);
                h3[rr] = fmaf(h2[rr][q * 4 + 2], w.z, h3[rr]);
                h3[rr] = fmaf(h2[rr][q * 4 + 3], w.w, h3[rr]);
            }
        }
#pragma unroll
        for (int rr = 0; rr < NR; ++rr) {
            srow[rr] += h3[rr];
            qrow[rr] = fmaf(h3[rr], h3[rr], qrow[rr]);
        }
    }
#pragma unroll
    for (int rr = 0; rr < NR; ++rr) {
        sd += (double)srow[rr];
        qd += (double)qrow[rr];
    }
}

__global__ void __launch_bounds__(TPB)
fancy_mlp_main(const float* __restrict__ x,
               const float* __restrict__ W,
               const float* __restrict__ bvec,
               const float* __restrict__ R,
               double* __restrict__ partS,
               double* __restrict__ partQ,
               long long nrows) {
    __shared__ __align__(16) float sM[D * D];
    __shared__ __align__(16) float sW[D * D];
    __shared__ float sC[D];
    __shared__ float sB[D];

    // Build fused constants per block (identical fp ops in every block -> deterministic).
    for (int t = threadIdx.x; t < D * D + D; t += TPB) {
        if (t < D * D) {
            int d = t / D, k = t % D;
            float s = 0.f;
#pragma unroll
            for (int j = 0; j < D; ++j) s = fmaf(W[j * D + d], R[j * D + k], s);
            sM[t] = s;       // M[d][k] = sum_j W[j][d] * R[j][k]
            sW[t] = W[t];
        } else {
            int k = t - D * D;
            float s = 1.f;
#pragma unroll
            for (int j = 0; j < D; ++j) s = fmaf(bvec[j], R[j * D + k], s);
            sC[k] = s;       // c[k] = 1 + sum_j b[j] * R[j][k]
            sB[k] = bvec[k];
        }
    }
    __syncthreads();

    long long gtid = (long long)blockIdx.x * TPB + threadIdx.x;
    long long gstride = (long long)gridDim.x * TPB;
    long long ngroups = nrows / NROWS;

    double sd = 0.0, qd = 0.0;
    for (long long g = gtid; g < ngroups; g += gstride) {
        process_rows<NROWS>(x + g * (NROWS * D), sM, sW, sC, sB, sd, qd);
    }
    // tail rows (nrows % NROWS), single-row path
    long long tr = ngroups * NROWS + gtid;
    if (tr < nrows) {
        process_rows<1>(x + tr * D, sM, sW, sC, sB, sd, qd);
    }

    // wave reduce (64 lanes)
#pragma unroll
    for (int off = 32; off > 0; off >>= 1) {
        sd += __shfl_down(sd, off);
        qd += __shfl_down(qd, off);
    }
    __shared__ double rS[TPB / 64], rQ[TPB / 64];
    int lane = threadIdx.x & 63;
    int wid = threadIdx.x >> 6;
    if (lane == 0) { rS[wid] = sd; rQ[wid] = qd; }
    __syncthreads();
    if (threadIdx.x == 0) {
        double S = 0.0, Q = 0.0;
#pragma unroll
        for (int w = 0; w < TPB / 64; ++w) { S += rS[w]; Q += rQ[w]; }
        partS[blockIdx.x] = S;
        partQ[blockIdx.x] = Q;
    }
}

__global__ void __launch_bounds__(256)
fancy_mlp_finish(const double* __restrict__ partS,
                 const double* __restrict__ partQ,
                 int nb, float* __restrict__ out) {
    double s = 0.0, q = 0.0;
    for (int i = threadIdx.x; i < nb; i += 256) { s += partS[i]; q += partQ[i]; }
#pragma unroll
    for (int off = 32; off > 0; off >>= 1) {
        s += __shfl_down(s, off);
        q += __shfl_down(q, off);
    }
    __shared__ double rS[4], rQ[4];
    int lane = threadIdx.x & 63;
    int wid = threadIdx.x >> 6;
    if (lane == 0) { rS[wid] = s; rQ[wid] = q; }
    __syncthreads();
    if (threadIdx.x == 0) {
        double S = rS[0] + rS[1] + rS[2] + rS[3];
        double Q = rQ[0] + rQ[1] + rQ[2] + rQ[3];
        float n = (float)sqrt(Q);
        // torch: while norm > 1: x /= 2  (halving exact in fp32)
        int k = 0;
        float nn = n;
        while (nn > 1.0f) { nn *= 0.5f; ++k; }
        float mult = (nn < 0.8f) ? 10.0f : 1.0f;
        double scale = ldexp(1.0, -k);
        out[0] = (float)(S * scale * (double)mult);
    }
}

extern "C" void kernel_launch(void* const* d_in, const int* in_sizes, int n_in,
                              void* d_out, int out_size, void* d_ws, size_t ws_size,
                              hipStream_t stream) {
    const float* x = (const float*)d_in[0];
    const float* W = (const float*)d_in[1];
    const float* b = (const float*)d_in[2];
    const float* R = (const float*)d_in[3];

    long long nrows = (long long)in_sizes[0] / D;      // 2,000,000
    long long ngroups = nrows / NROWS;                 // 500,000
    long long want_blocks = (ngroups + TPB - 1) / TPB; // ~1954
    long long maxb = (long long)(ws_size / (2 * sizeof(double)));
    long long nb = want_blocks;
    if (nb > maxb) nb = maxb;
    if (nb < 1) nb = 1;
    int nblocks = (int)nb;

    double* partS = (double*)d_ws;
    double* partQ = partS + nblocks;

    fancy_mlp_main<<<nblocks, TPB, 0, stream>>>(x, W, b, R, partS, partQ, nrows);
    fancy_mlp_finish<<<1, 256, 0, stream>>>(partS, partQ, nblocks, (float*)d_out);
}

// Round 2
// 333.460 us; speedup vs baseline: 3.4601x; 3.4601x over previous
//
#include <hip/hip_runtime.h>
#include <hip/hip_bf16.h>
#include <math.h>

#define D 20
#define NROWS 4
#define TPB 256
#define WS_CONST_BYTES 2048   // Mc region at front of ws: 400 M + 20 c floats

// Fused per-row pipeline:
//   h2 = relu(x @ M + c)   with M = W^T R (DxD), c = 1 + b @ R
//   h3 = h2 @ W^T + b
//   accumulate S += sum(h3), Q += sum(h3^2)
// Constants are read from GLOBAL memory with wave-uniform indices so the
// compiler emits s_load -> SGPR operands on the FMAs (zero VGPR cost).
// x is streamed float4-at-a-time so no xr[][] array exists (R1 spilled).
template <int NR>
__device__ __forceinline__ void process_rows_g(const float* __restrict__ xp,
                                               const float* __restrict__ Mc,
                                               const float* __restrict__ W,
                                               const float* __restrict__ bvec,
                                               double& sd, double& qd) {
    float h2[NR][D];
#pragma unroll
    for (int k = 0; k < D; ++k) {
        float c = Mc[D * D + k];
#pragma unroll
        for (int rr = 0; rr < NR; ++rr) h2[rr][k] = c;
    }

    const float4* xp4 = (const float4*)xp;
#pragma unroll
    for (int q = 0; q < D / 4; ++q) {
        float4 xv[NR];
#pragma unroll
        for (int rr = 0; rr < NR; ++rr) xv[rr] = xp4[rr * (D / 4) + q];
#pragma unroll
        for (int dd = 0; dd < 4; ++dd) {
            const int d = q * 4 + dd;
#pragma unroll
            for (int k = 0; k < D; ++k) {
                float m = Mc[d * D + k];
#pragma unroll
                for (int rr = 0; rr < NR; ++rr) {
                    float xs = (dd == 0) ? xv[rr].x
                             : (dd == 1) ? xv[rr].y
                             : (dd == 2) ? xv[rr].z
                                         : xv[rr].w;
                    h2[rr][k] = fmaf(xs, m, h2[rr][k]);
                }
            }
        }
    }

#pragma unroll
    for (int rr = 0; rr < NR; ++rr)
#pragma unroll
        for (int k = 0; k < D; ++k) h2[rr][k] = fmaxf(h2[rr][k], 0.f);

    float srow[NR], qrow[NR];
#pragma unroll
    for (int rr = 0; rr < NR; ++rr) { srow[rr] = 0.f; qrow[rr] = 0.f; }

#pragma unroll
    for (int j = 0; j < D; ++j) {
        float bj = bvec[j];
        float h3[NR];
#pragma unroll
        for (int rr = 0; rr < NR; ++rr) h3[rr] = bj;
#pragma unroll
        for (int k = 0; k < D; ++k) {
            float w = W[j * D + k];
#pragma unroll
            for (int rr = 0; rr < NR; ++rr) h3[rr] = fmaf(h2[rr][k], w, h3[rr]);
        }
#pragma unroll
        for (int rr = 0; rr < NR; ++rr) {
            srow[rr] += h3[rr];
            qrow[rr] = fmaf(h3[rr], h3[rr], qrow[rr]);
        }
    }
#pragma unroll
    for (int rr = 0; rr < NR; ++rr) {
        sd += (double)srow[rr];
        qd += (double)qrow[rr];
    }
}

// Tiny prep: Mc[0..399] = M (W^T R), Mc[400..419] = c (1 + b@R).
__global__ void __launch_bounds__(256)
fancy_mlp_prep(const float* __restrict__ W, const float* __restrict__ bvec,
               const float* __restrict__ R, float* __restrict__ Mc) {
    int t = blockIdx.x * 256 + threadIdx.x;
    if (t < D * D) {
        int d = t / D, k = t % D;
        float s = 0.f;
#pragma unroll
        for (int j = 0; j < D; ++j) s = fmaf(W[j * D + d], R[j * D + k], s);
        Mc[t] = s;
    } else if (t < D * D + D) {
        int k = t - D * D;
        float s = 1.f;
#pragma unroll
        for (int j = 0; j < D; ++j) s = fmaf(bvec[j], R[j * D + k], s);
        Mc[t] = s;
    }
}

__global__ void __launch_bounds__(TPB)
fancy_mlp_main(const float* __restrict__ x,
               const float* __restrict__ W,
               const float* __restrict__ bvec,
               const float* __restrict__ Mc,
               double* __restrict__ partS,
               double* __restrict__ partQ,
               long long nrows) {
    long long gtid = (long long)blockIdx.x * TPB + threadIdx.x;
    long long gstride = (long long)gridDim.x * TPB;
    long long ngroups = nrows / NROWS;

    double sd = 0.0, qd = 0.0;
    for (long long g = gtid; g < ngroups; g += gstride) {
        process_rows_g<NROWS>(x + g * (NROWS * D), Mc, W, bvec, sd, qd);
    }
    long long tr = ngroups * NROWS + gtid;
    if (tr < nrows) {
        process_rows_g<1>(x + tr * D, Mc, W, bvec, sd, qd);
    }

    // wave(64) shuffle reduce, then per-block partial
#pragma unroll
    for (int off = 32; off > 0; off >>= 1) {
        sd += __shfl_down(sd, off);
        qd += __shfl_down(qd, off);
    }
    __shared__ double rS[TPB / 64], rQ[TPB / 64];
    int lane = threadIdx.x & 63;
    int wid = threadIdx.x >> 6;
    if (lane == 0) { rS[wid] = sd; rQ[wid] = qd; }
    __syncthreads();
    if (threadIdx.x == 0) {
        double S = 0.0, Q = 0.0;
#pragma unroll
        for (int w = 0; w < TPB / 64; ++w) { S += rS[w]; Q += rQ[w]; }
        partS[blockIdx.x] = S;
        partQ[blockIdx.x] = Q;
    }
}

__global__ void __launch_bounds__(256)
fancy_mlp_finish(const double* __restrict__ partS,
                 const double* __restrict__ partQ,
                 int nb, float* __restrict__ out) {
    double s = 0.0, q = 0.0;
    for (int i = threadIdx.x; i < nb; i += 256) { s += partS[i]; q += partQ[i]; }
#pragma unroll
    for (int off = 32; off > 0; off >>= 1) {
        s += __shfl_down(s, off);
        q += __shfl_down(q, off);
    }
    __shared__ double rS[4], rQ[4];
    int lane = threadIdx.x & 63;
    int wid = threadIdx.x >> 6;
    if (lane == 0) { rS[wid] = s; rQ[wid] = q; }
    __syncthreads();
    if (threadIdx.x == 0) {
        double S = rS[0] + rS[1] + rS[2] + rS[3];
        double Q = rQ[0] + rQ[1] + rQ[2] + rQ[3];
        float n = (float)sqrt(Q);
        // torch: while norm > 1: x /= 2  (halving exact in fp32)
        int k = 0;
        float nn = n;
        while (nn > 1.0f) { nn *= 0.5f; ++k; }
        float mult = (nn < 0.8f) ? 10.0f : 1.0f;
        double scale = ldexp(1.0, -k);
        out[0] = (float)(S * scale * (double)mult);
    }
}

extern "C" void kernel_launch(void* const* d_in, const int* in_sizes, int n_in,
                              void* d_out, int out_size, void* d_ws, size_t ws_size,
                              hipStream_t stream) {
    const float* x = (const float*)d_in[0];
    const float* W = (const float*)d_in[1];
    const float* b = (const float*)d_in[2];
    const float* R = (const float*)d_in[3];

    float* Mc = (float*)d_ws;
    char* wsp = (char*)d_ws + WS_CONST_BYTES;
    size_t ws_rem = (ws_size > WS_CONST_BYTES) ? ws_size - WS_CONST_BYTES : 0;

    long long nrows = (long long)in_sizes[0] / D;      // 2,000,000
    long long ngroups = nrows / NROWS;                 // 500,000
    long long want_blocks = (ngroups + TPB - 1) / TPB; // ~1954
    long long maxb = (long long)(ws_rem / (2 * sizeof(double)));
    long long nb = want_blocks;
    if (nb > maxb) nb = maxb;
    if (nb < 1) nb = 1;
    int nblocks = (int)nb;

    double* partS = (double*)wsp;
    double* partQ = partS + nblocks;

    fancy_mlp_prep<<<2, 256, 0, stream>>>(W, b, R, Mc);
    fancy_mlp_main<<<nblocks, TPB, 0, stream>>>(x, W, b, Mc, partS, partQ, nrows);
    fancy_mlp_finish<<<1, 256, 0, stream>>>(partS, partQ, nblocks, (float*)d_out);
}